// Round 13
// baseline (349.139 us; speedup 1.0000x reference)
//
#include <hip/hip_runtime.h>
#include <hip/hip_bf16.h>
#include <math.h>

// MFGN forward, MI355X. One block (512 thr, 8 waves) per outfit.
// R26: the decisive 3-blocks/CU experiment. Insight: gfx950 unified
// VGPR/AGPR file -> rocprof VGPR_Count (56) is ARCH-ONLY; + 32 hidden
// acc AGPRs = 88 total > 85 = floor(512regs / 6waves-per-SIMD). R15's
// 3-block try fixed LDS but not this. No round attacked BOTH. Changes:
//  - LDS alloc 54,272 B (x3 = 162.8KB <= 163.84KB): facL repacked to
//    item-stride 516 / f-stride 128 (33.0KB, float4-aligned, mod32=4);
//    prodS+hidS MERGED into bufS (WAR barriers: 4/B-step, +16 total
//    ~ +2.5us by R17 calibration); scalar arrays as chars (R15-proven).
//  - Register peak shave: w2f loaded LATE (after L1 MFMA chain) in
//    B/C/D so w1f/w2f never co-live -> arch ~50, total ~82 <= 85.
//  - __launch_bounds__(512,3).
// Arithmetic/order identical to R22 (absmax bit-stable expected).
// Success: occupancy ~63%, ~175-188us. Refuted: ~43%, ~211-218us ->
// 3-block path dead for non-register reasons, R22 terminal.
// Laws: segment latency is the lever (R18 -21us, setprio -7us); barrier
// count cheap (R17); pipelining/F-fusion/stride-games null (R19-R25).

typedef __attribute__((ext_vector_type(8))) short short8;
typedef __attribute__((ext_vector_type(4))) float f32x4;

#define MFMA16(a, b, c) __builtin_amdgcn_mfma_f32_16x16x32_bf16(a, b, c, 0, 0, 0)

__device__ __forceinline__ float lrelu(float x) { return fmaxf(x, 0.01f * x); }

__device__ __forceinline__ ushort f2bf(float f) {
  unsigned u = __builtin_bit_cast(unsigned, f);
  u += 0x7fffu + ((u >> 16) & 1u);  // RNE
  return (ushort)(u >> 16);
}
__device__ __forceinline__ float bflo(unsigned u) {
  return __builtin_bit_cast(float, u << 16);
}
__device__ __forceinline__ unsigned pk2(float a, float b) {
  float2 t; t.x = a; t.y = b;
  __hip_bfloat162 h = __float22bfloat162_rn(t);
  unsigned u;
  __builtin_memcpy(&u, &h, 4);
  return u;
}

// d_ws layout (ushort): cfW1T@0 [4][64n][128k] | cfW2T@32768 [4][128n][64k]
// | f2fW1T@65536 | f2fW2T@81920 | f2iW1T@98304 | f2iW2T@114688
// | i2iW1T@131072 | i2iW2T@147456   ([128n][128k] each; 320KB total)

__global__ __launch_bounds__(256) void prep_weights(
    const float* __restrict__ cfW1, const float* __restrict__ cfW2,
    const float* __restrict__ f2fW1, const float* __restrict__ f2fW2,
    const float* __restrict__ f2iW1, const float* __restrict__ f2iW2,
    const float* __restrict__ i2iW1, const float* __restrict__ i2iW2,
    ushort* __restrict__ ws, float* __restrict__ out) {
  const int idx = (int)(blockIdx.x * 256 + threadIdx.x);
  if (idx == 0) out[2048] = 0.0f;  // com accumulator zero
  float v;
  if (idx < 32768) {          // cfW1 [f][k<128][n<64] -> [f][n][k]
    int f = idx >> 13, r = idx & 8191, n = r >> 7, k = r & 127;
    v = cfW1[f * 8192 + k * 64 + n];
  } else if (idx < 65536) {   // cfW2 [f][k<64][n<128] -> [f][n][k]
    int t = idx - 32768;
    int f = t >> 13, r = t & 8191, n = r >> 6, k = r & 63;
    v = cfW2[f * 8192 + k * 128 + n];
  } else {                    // 6 x [k<128][n<128] -> [n][k]
    int t = idx - 65536;
    int seg = t >> 14, r = t & 16383, n = r >> 7, k = r & 127;
    const float* W = (seg == 0) ? f2fW1 : (seg == 1) ? f2fW2 :
                     (seg == 2) ? f2iW1 : (seg == 3) ? f2iW2 :
                     (seg == 4) ? i2iW1 : i2iW2;
    v = W[k * 128 + n];
  }
  ws[idx] = f2bf(v);
}

__global__ __launch_bounds__(512, 3) void mfgn_kernel(
    const int* __restrict__ outfit_items,
    const float* __restrict__ items_feature,
    const int* __restrict__ items_neighbor,
    const float* __restrict__ cfb1, const float* __restrict__ cfb2,
    const float* __restrict__ f2fb1, const float* __restrict__ f2fb2,
    const float* __restrict__ f2ib1, const float* __restrict__ f2ib2,
    const float* __restrict__ i2ib1, const float* __restrict__ i2ib2,
    const float* __restrict__ o2sW, const float* __restrict__ o2sb,
    const ushort* __restrict__ wsW,
    float* __restrict__ out)
{
  __shared__ float facL[16 * 516];                                // 33024 B fp32 state
  __shared__ ushort bufS[8192] __attribute__((aligned(16)));      // 16384 B prod+hid frags
  __shared__ ushort featB[2048] __attribute__((aligned(16)));     //  4096 B
  __shared__ float redE[8];
  __shared__ signed char oiL[16];
  __shared__ unsigned char clAllU[256];
  __shared__ unsigned char ncAll[16];
  __shared__ unsigned char vslL[16];
  __shared__ unsigned char refcntL[16];
  __shared__ int nvsL;
  // static ~53,860 B -> alloc 54,272 -> 3 blocks/CU (162,816 of 163,840)
  // facL: item stride 516 floats (mod32=4 -> 8 bank-slot spread), f
  // stride 128, float4-aligned everywhere.
  // frag unit (mt,kt,l): 8 ushorts at (kt*4+mt)*512 + l*8 in bufS.
  // unit holds X[row = mt*16 + (l&15)][k = kt*32 + (l>>4)*8 .. +8].
  // fragment read = base + lane*16B -> contiguous, conflict-free.
  // featB: units (kt): kt*512 + l*8; element (row,c) at
  // (c>>5)*512 + (((c>>3)&3)*16 + row)*8 + (c&7).

  const int o = blockIdx.x;
  const int tid = (int)threadIdx.x;
  const int lane = tid & 63;
  const int wid = tid >> 6;        // wave owns output cols wid*16..+15
  const int n16 = lane & 15;
  const int q = lane >> 4;
  const int kb = q * 8;
  const int col = wid * 16 + n16;
  const int lx = lane * 8;         // fragment lane offset (ushorts)
  // col-partitioned staging: lane = prod row; wave owns k-cols [wid*16,+16)
  const int fS = lane & 3, ciS = lane >> 2;
  const int kc0 = wid * 16;
  const int q0 = (wid & 1) * 2;    // staged k-chunks are q-slots q0,q0+1 of kt=wid>>1
  const int sWA = ((wid >> 1) * 4 + (lane >> 4)) * 512 + (lane & 15) * 8;
  // hid write base for B/C (add mt*512) and D (mt=0)
  const int hwB = (wid >> 1) * 2048 + ((wid & 1) * 2 + (q >> 1)) * 128 + n16 * 8 + (q & 1) * 4;
  // featB element base for this lane's col (add item*8)
  const int fbCol = (col >> 5) * 512 + ((col >> 3) & 3) * 128 + (col & 7);

  // ---------------- load inputs ----------------
  if (tid < 16) oiL[tid] = (signed char)outfit_items[o * 16 + tid];
  {
    const int n = tid >> 5, d0 = (tid & 31) * 4;
    float4 v = *(const float4*)(items_feature + o * 2048 + tid * 4);
    uint2 pk; pk.x = pk2(v.x, v.y); pk.y = pk2(v.z, v.w);
    *(uint2*)(featB + (d0 >> 5) * 512 + (((d0 >> 3) & 3) * 16 + n) * 8 + (d0 & 7)) = pk;
  }
  if (tid == 0) {
    int cnt = 0;
    int rc[16];
    for (int s = 0; s < 16; ++s) rc[s] = 0;
    for (int s = 0; s < 16; ++s) {
      int v = (int)oiL[s];
      if (v != -1) { vslL[cnt++] = (unsigned char)s; rc[v]++; }
    }
    for (int s = 0; s < 16; ++s) refcntL[s] = (unsigned char)rc[s];
    nvsL = cnt;
  }
  for (int s = wid; s < 16; s += 8) {
    const int iv = outfit_items[o * 16 + s];
    if (iv == -1) { if (lane == 0) ncAll[s] = 0; continue; }
    int cand = -1;
    if (lane < 24) cand = (lane < 16) ? outfit_items[o * 16 + lane]
                                      : items_neighbor[o * 128 + iv * 8 + (lane - 16)];
    bool ok = (lane < 24) && (cand != -1) && (cand != iv);
    unsigned long long bm = __ballot(ok);
    if (ok) clAllU[s * 16 + __popcll(bm & ((1ull << lane) - 1ull))] = (unsigned char)cand;
    if (lane == 0) ncAll[s] = (unsigned char)__popcll(bm);
  }
  __syncthreads();
  const int nvs = nvsL;

  // ---------------- Phase A: creat_factors ----------------
  {
    const int f = wid & 3, half = wid >> 2;
    short8 wA[2][4];
#pragma unroll
    for (int etl = 0; etl < 2; ++etl)
#pragma unroll
      for (int kt = 0; kt < 4; ++kt)
        wA[etl][kt] = *(const short8*)(wsW + (f * 64 + (half * 2 + etl) * 16 + n16) * 128
                                       + kt * 32 + kb);
    f32x4 acc[2];
#pragma unroll
    for (int etl = 0; etl < 2; ++etl)
      acc[etl] = *(const f32x4*)(cfb1 + f * 64 + (half * 2 + etl) * 16 + q * 4);  // bias init
    __builtin_amdgcn_s_setprio(1);
    for (int kt = 0; kt < 4; ++kt) {
      short8 x = *(const short8*)(featB + kt * 512 + lx);
      acc[0] = MFMA16(wA[0][kt], x, acc[0]);
      acc[1] = MFMA16(wA[1][kt], x, acc[1]);
    }
    __builtin_amdgcn_s_setprio(0);
#pragma unroll
    for (int etl = 0; etl < 2; ++etl) {
      float h0 = lrelu(acc[etl][0]), h1 = lrelu(acc[etl][1]);
      float h2 = lrelu(acc[etl][2]), h3 = lrelu(acc[etl][3]);
      uint2 pk; pk.x = pk2(h0, h1); pk.y = pk2(h2, h3);
      // hid row f*16+n16, cols (half*2+etl)*16 + q*4 .. +3 (D2=64, kt_h=half)
      *(uint2*)(bufS + half * 2048 + f * 512 + (etl * 2 + (q >> 1)) * 128
                + n16 * 8 + (q & 1) * 4) = pk;
    }
    __syncthreads();
    short8 wB[4][2];
#pragma unroll
    for (int ctl = 0; ctl < 4; ++ctl)
#pragma unroll
      for (int kt = 0; kt < 2; ++kt)
        wB[ctl][kt] = *(const short8*)(wsW + 32768 + (f * 128 + half * 64 + ctl * 16 + n16) * 64
                                       + kt * 32 + kb);
    f32x4 acc2[4];
#pragma unroll
    for (int ctl = 0; ctl < 4; ++ctl) {
      float b2 = cfb2[f * 128 + half * 64 + ctl * 16 + n16];
      acc2[ctl] = (f32x4){b2, b2, b2, b2};  // bias init
    }
    __builtin_amdgcn_s_setprio(1);
    for (int kt = 0; kt < 2; ++kt) {
      short8 h = *(const short8*)(bufS + (kt * 4 + f) * 512 + lx);
#pragma unroll
      for (int ctl = 0; ctl < 4; ++ctl) acc2[ctl] = MFMA16(h, wB[ctl][kt], acc2[ctl]);
    }
    __builtin_amdgcn_s_setprio(0);
#pragma unroll
    for (int ctl = 0; ctl < 4; ++ctl) {
      int c = half * 64 + ctl * 16 + n16;
#pragma unroll
      for (int r = 0; r < 4; ++r)
        facL[(q * 4 + r) * 516 + f * 128 + c] = lrelu(acc2[ctl][r]);
    }
    __syncthreads();
  }

  // ---------------- Phase B: inter_factors (shared bufS, 4 barriers/step) ----------------
  {
    short8 w1f[4];
#pragma unroll
    for (int kt = 0; kt < 4; ++kt)
      w1f[kt] = *(const short8*)(wsW + 65536 + col * 128 + kt * 32 + kb);
    const f32x4 b1q = *(const f32x4*)(f2fb1 + wid * 16 + q * 4);
    const float b2v = f2fb2[col];

    // stage prod rows for slot s into frag layout (this wave's k-cols only)
    auto stageB = [&](int s, int iv_, int nc_) {
      if (ciS < nc_) {
        const int cit = (int)clAllU[s * 16 + ciS];
        const float* tp = facL + iv_ * 516 + fS * 128 + kc0;
        const float* cp = facL + cit * 516 + fS * 128 + kc0;
#pragma unroll
        for (int g = 0; g < 2; ++g) {
          float4 a0 = *(const float4*)(tp + g * 8), a1 = *(const float4*)(tp + g * 8 + 4);
          float4 c0 = *(const float4*)(cp + g * 8), c1 = *(const float4*)(cp + g * 8 + 4);
          uint4 u4;
          u4.x = pk2(a0.x * c0.x, a0.y * c0.y); u4.y = pk2(a0.z * c0.z, a0.w * c0.w);
          u4.z = pk2(a1.x * c1.x, a1.y * c1.y); u4.w = pk2(a1.z * c1.z, a1.w * c1.w);
          *(uint4*)(bufS + sWA + (q0 + g) * 128) = u4;
        }
      }
      // rows >= 4*nc stale: finite bf16, epilogue-masked (MLP row-separable)
    };
    // stage Phase C's input: bf16(fac[item=ciS][fS][k]) in frag layout
    auto stageC = [&]() {
      const float* sp = facL + ciS * 516 + fS * 128 + kc0;
#pragma unroll
      for (int g = 0; g < 2; ++g) {
        float4 a0 = *(const float4*)(sp + g * 8), a1 = *(const float4*)(sp + g * 8 + 4);
        uint4 u4;
        u4.x = pk2(a0.x, a0.y); u4.y = pk2(a0.z, a0.w);
        u4.z = pk2(a1.x, a1.y); u4.w = pk2(a1.z, a1.w);
        *(uint4*)(bufS + sWA + (q0 + g) * 128) = u4;
      }
    };

    // prologue: A's bufS reads are behind A's final barrier; safe to stage.
    if (nvs > 0) { const int s0 = vslL[0]; stageB(s0, (int)oiL[s0], (int)ncAll[s0]); }
    __syncthreads();  // [b1] products for step 0 ready

    for (int u = 0; u < nvs; ++u) {
      const int s = (int)vslL[u];
      const int iv = (int)oiL[s];
      const int nc = (int)ncAll[s];
      // L1 swapped: unrolled 4 tiles, bias-initialized acc
      f32x4 acc[4];
#pragma unroll
      for (int mt = 0; mt < 4; ++mt) acc[mt] = b1q;
      __builtin_amdgcn_s_setprio(1);
      for (int kt = 0; kt < 4; ++kt)
#pragma unroll
        for (int mt = 0; mt < 4; ++mt) {
          short8 x = *(const short8*)(bufS + (kt * 4 + mt) * 512 + lx);
          acc[mt] = MFMA16(w1f[kt], x, acc[mt]);
        }
      __builtin_amdgcn_s_setprio(0);
      // w2f loaded LATE (after L1 chain) so w1f/w2f never co-live: reg shave
      short8 w2f[4];
#pragma unroll
      for (int kt = 0; kt < 4; ++kt)
        w2f[kt] = *(const short8*)(wsW + 81920 + col * 128 + kt * 32 + kb);
      __syncthreads();  // [b1.5] all prod reads drained before hid overwrite
#pragma unroll
      for (int mt = 0; mt < 4; ++mt) {
        float h0 = lrelu(acc[mt][0]), h1 = lrelu(acc[mt][1]);
        float h2 = lrelu(acc[mt][2]), h3 = lrelu(acc[mt][3]);
        uint2 pk; pk.x = pk2(h0, h1); pk.y = pk2(h2, h3);
        *(uint2*)(bufS + hwB + mt * 512) = pk;
      }
      __syncthreads();  // [b2] hid ready
      // L2 normal: unrolled 4 tiles, bias-initialized acc
      f32x4 acc2[4];
#pragma unroll
      for (int mt = 0; mt < 4; ++mt) acc2[mt] = (f32x4){b2v, b2v, b2v, b2v};
      __builtin_amdgcn_s_setprio(1);
      for (int kt = 0; kt < 4; ++kt)
#pragma unroll
        for (int mt = 0; mt < 4; ++mt) {
          short8 h = *(const short8*)(bufS + (kt * 4 + mt) * 512 + lx);
          acc2[mt] = MFMA16(h, w2f[kt], acc2[mt]);
        }
      __builtin_amdgcn_s_setprio(0);
      // epilogue: rows ci*4+f (f=reg); mask ci=mt*4+q<nc; sum over ci
      float part[4] = {0.f, 0.f, 0.f, 0.f};
#pragma unroll
      for (int mt = 0; mt < 4; ++mt) {
        bool act = (mt * 4 + q) < nc;
        if (act) {
#pragma unroll
          for (int r = 0; r < 4; ++r) part[r] += lrelu(acc2[mt][r]);
        }
      }
#pragma unroll
      for (int r = 0; r < 4; ++r) {
        float v = part[r];
        v += __shfl_xor(v, 16);
        v += __shfl_xor(v, 32);
        part[r] = v;
      }
      if (q == 0) {  // wave owns cols exclusively -> plain fp32 +=
#pragma unroll
        for (int r = 0; r < 4; ++r)
          facL[iv * 516 + r * 128 + col] += part[r];
      }
      __syncthreads();  // [b2.5] all hid reads drained before prod overwrite
      // stage next: update above touched only this wave's cols; staging
      // reads only this wave's cols -> same-wave DS order suffices.
      if (u + 1 < nvs) {
        const int s2 = (int)vslL[u + 1];
        stageB(s2, (int)oiL[s2], (int)ncAll[s2]);
      } else {
        stageC();
      }
      __syncthreads();  // [b1] next products (or Phase C input) ready
    }
    if (nvs == 0) { stageC(); __syncthreads(); }  // robustness (unused outputs)
  }

  // ---------------- Phase C: infer_items (input pre-staged by B) ----------------
  {
    short8 w1f[4];
#pragma unroll
    for (int kt = 0; kt < 4; ++kt)
      w1f[kt] = *(const short8*)(wsW + 98304 + col * 128 + kt * 32 + kb);
    const f32x4 b1q = *(const f32x4*)(f2ib1 + wid * 16 + q * 4);
    const float b2v = f2ib2[col];
    f32x4 acc[4];
#pragma unroll
    for (int mt = 0; mt < 4; ++mt) acc[mt] = b1q;
    __builtin_amdgcn_s_setprio(1);
    for (int kt = 0; kt < 4; ++kt)
#pragma unroll
      for (int mt = 0; mt < 4; ++mt) {
        short8 x = *(const short8*)(bufS + (kt * 4 + mt) * 512 + lx);
        acc[mt] = MFMA16(w1f[kt], x, acc[mt]);
      }
    __builtin_amdgcn_s_setprio(0);
    short8 w2f[4];  // late load (reg shave)
#pragma unroll
    for (int kt = 0; kt < 4; ++kt)
      w2f[kt] = *(const short8*)(wsW + 114688 + col * 128 + kt * 32 + kb);
    __syncthreads();  // WAR: prod reads drained before hid overwrite
#pragma unroll
    for (int mt = 0; mt < 4; ++mt) {
      float h0 = lrelu(acc[mt][0]), h1 = lrelu(acc[mt][1]);
      float h2 = lrelu(acc[mt][2]), h3 = lrelu(acc[mt][3]);
      uint2 pk; pk.x = pk2(h0, h1); pk.y = pk2(h2, h3);
      *(uint2*)(bufS + hwB + mt * 512) = pk;
    }
    __syncthreads();
    f32x4 acc2[4];
#pragma unroll
    for (int mt = 0; mt < 4; ++mt) acc2[mt] = (f32x4){b2v, b2v, b2v, b2v};
    __builtin_amdgcn_s_setprio(1);
    for (int kt = 0; kt < 4; ++kt)
#pragma unroll
      for (int mt = 0; mt < 4; ++mt) {
        short8 h = *(const short8*)(bufS + (kt * 4 + mt) * 512 + lx);
        acc2[mt] = MFMA16(h, w2f[kt], acc2[mt]);
      }
    __builtin_amdgcn_s_setprio(0);
#pragma unroll
    for (int mt = 0; mt < 4; ++mt) {
      int item = mt * 4 + q;  // rows = item*4+f, f=reg
      float g = 0.f;
#pragma unroll
      for (int r = 0; r < 4; ++r) g += lrelu(acc2[mt][r]);
      int a = fbCol + item * 8;  // unique (item,col) per lane
      featB[a] = f2bf(bflo((unsigned)featB[a]) + (float)refcntL[item] * g);
    }
    __syncthreads();
  }

  // ---------------- Phase D: inter_items (featB A-fragments reg-cached) ----------------
  {
    short8 w1f[4];
#pragma unroll
    for (int kt = 0; kt < 4; ++kt)
      w1f[kt] = *(const short8*)(wsW + 131072 + col * 128 + kt * 32 + kb);
    const f32x4 b1q = *(const f32x4*)(i2ib1 + wid * 16 + q * 4);
    const float b2v = i2ib2[col];
    short8 xc[4];
#pragma unroll
    for (int kt = 0; kt < 4; ++kt)
      xc[kt] = *(const short8*)(featB + kt * 512 + lx);

    for (int u = 0; u < nvs; ++u) {
      const int iv = (int)oiL[(int)vslL[u]];
      f32x4 acc = b1q;
      __builtin_amdgcn_s_setprio(1);
      for (int kt = 0; kt < 4; ++kt) acc = MFMA16(w1f[kt], xc[kt], acc);
      __builtin_amdgcn_s_setprio(0);
      short8 w2f[4];  // late load per step (reg shave; L1$-hot after u=0)
#pragma unroll
      for (int kt = 0; kt < 4; ++kt)
        w2f[kt] = *(const short8*)(wsW + 147456 + col * 128 + kt * 32 + kb);
      {
        float h0 = lrelu(acc[0]), h1 = lrelu(acc[1]);
        float h2 = lrelu(acc[2]), h3 = lrelu(acc[3]);
        uint2 pk; pk.x = pk2(h0, h1); pk.y = pk2(h2, h3);
        *(uint2*)(bufS + hwB) = pk;   // rows n16 -> mt=0 frags
      }
      __syncthreads();
      f32x4 acc2 = (f32x4){b2v, b2v, b2v, b2v};
      __builtin_amdgcn_s_setprio(1);
      for (int kt = 0; kt < 4; ++kt) {
        short8 h = *(const short8*)(bufS + kt * 2048 + lx);
        acc2 = MFMA16(h, w2f[kt], acc2);
      }
      __builtin_amdgcn_s_setprio(0);
      // msgs summed per item with weight = (item==iv) ? 0 : refcnt[item]
      float part = 0.f;
#pragma unroll
      for (int r = 0; r < 4; ++r) {
        int item = q * 4 + r;
        float w = (item == iv) ? 0.0f : (float)refcntL[item];
        part += w * lrelu(acc2[r]);
      }
      part += __shfl_xor(part, 16);
      part += __shfl_xor(part, 32);
      if (q == 0) {
        int a = fbCol + iv * 8;
        featB[a] = f2bf(bflo((unsigned)featB[a]) + part);
      }
      __syncthreads();
      // refresh cached featB row iv (only lanes whose fragment row changed);
      // next update happens only after the next barrier -> no race
      if (n16 == iv) {
#pragma unroll
        for (int kt = 0; kt < 4; ++kt)
          xc[kt] = *(const short8*)(featB + kt * 512 + lx);
      }
    }
  }

  // ---------------- Phase E: infer_outfit + score ----------------
  if (tid < 128) {
    const int eb = (tid >> 5) * 512 + ((tid >> 3) & 3) * 128 + (tid & 7);
    float sum = 0.0f;
    for (int u = 0; u < nvs; ++u) {
      int it = (int)oiL[(int)vslL[u]];
      sum += bflo((unsigned)featB[eb + it * 8]);
    }
    float v = sum * o2sW[tid];
#pragma unroll
    for (int off = 1; off < 64; off <<= 1) v += __shfl_xor(v, off);
    if (lane == 0) redE[wid] = v;
  }
  __syncthreads();
  if (tid == 0) {
    float t = redE[0] + redE[1] + o2sb[0];
    out[o] = 1.0f / (1.0f + expf(-t));
  }

  // ---------------- Phase F: com_loss (symmetric: f<=g only, x2 off-diag) ----------------
  {
    const int n = tid >> 5, f = (tid >> 3) & 3, g = (tid >> 1) & 3, h = tid & 1;
    float dot = 0.0f;
    if (f <= g) {
      const float* pa = facL + n * 516 + f * 128 + h * 64;
      const float* pb = facL + n * 516 + g * 128 + h * 64;
      for (int i = 0; i < 16; ++i) {
        float4 a = *(const float4*)(pa + i * 4);
        float4 b = *(const float4*)(pb + i * 4);
        dot += a.x * b.x + a.y * b.y + a.z * b.z + a.w * b.w;
      }
    }
    dot += __shfl_xor(dot, 1);  // combine k-halves
    float v = dot - ((f == g) ? 1.0f : 0.0f);
    float wgt = (f == g) ? 1.0f : 2.0f;
    float sq = (h == 0 && f <= g && oiL[n] != -1) ? wgt * v * v : 0.0f;
#pragma unroll
    for (int off = 1; off < 64; off <<= 1) sq += __shfl_xor(sq, off);
    __syncthreads();  // E's redE read complete before overwrite
    if (lane == 0) redE[wid] = sq;
    __syncthreads();
    if (tid == 0) {
      float tot = 0.f;
#pragma unroll
      for (int w = 0; w < 8; ++w) tot += redE[w];
      atomicAdd(out + 2048, tot * (1.0f / 2048.0f));
    }
  }
}

extern "C" void kernel_launch(void* const* d_in, const int* in_sizes, int n_in,
                              void* d_out, int out_size, void* d_ws, size_t ws_size,
                              hipStream_t stream) {
  float* out = (float*)d_out;
  ushort* ws = (ushort*)d_ws;  // needs 320KB
  hipLaunchKernelGGL(prep_weights, dim3(640), dim3(256), 0, stream,
                     (const float*)d_in[4], (const float*)d_in[6],
                     (const float*)d_in[8], (const float*)d_in[10],
                     (const float*)d_in[12], (const float*)d_in[14],
                     (const float*)d_in[16], (const float*)d_in[18],
                     ws, out);
  hipLaunchKernelGGL(mfgn_kernel, dim3(2048), dim3(512), 0, stream,
                     (const int*)d_in[0],
                     (const float*)d_in[1],
                     (const int*)d_in[2],
                     // d_in[3] items_factors unused; weights via ws
                     (const float*)d_in[5], (const float*)d_in[7],
                     (const float*)d_in[9], (const float*)d_in[11],
                     (const float*)d_in[13], (const float*)d_in[15],
                     (const float*)d_in[17], (const float*)d_in[19],
                     (const float*)d_in[20], (const float*)d_in[21],
                     (const ushort*)ws,
                     out);
}

// Round 14
// 316.195 us; speedup vs baseline: 1.1042x; 1.1042x over previous
//
#include <hip/hip_runtime.h>
#include <hip/hip_bf16.h>
#include <math.h>

// MFGN forward, MI355X. One block (512 thr, 8 waves) per outfit.
// R27 = R22 RESTORED (session best, 208.6us) as the terminal kernel.
// R26's decisive 3-block experiment REFUTED occupancy recovery: LDS
// 54,272 (x3 fits 160KiB), VGPR 56, launch_bounds(512,3) -> occupancy
// STILL 43% (2 blocks). The 2-block ceiling is a hidden scheduler/
// allocation constraint, not HIP-addressable. R26 also re-proved the
// conflict algebra (f-stride 128 -> conflicts 3.6x, 241us).
// Final ledger: frag-major LDS (R18, -21us) + setprio T5 (R22, -7us)
// are the only real wins. Falsified: 3 blk/CU (R15/R26), bigger tiles
// (R16/R21 -> 1 blk, catastrophic), barrier diet (R17, ~1us), staging
// pipelining (R19/R20, negative), F-fusion (R24, neutral), stride
// re-banking (R25, neutral). Kernel is latency-bound on the semantics-
// mandated serial scan at a hardware-pinned 2-block residency:
// MfmaUtil 20 / VALUBusy 44 / HBM 0.6% / conflicts 6%.
// R22 core: fragment-major prodS/hidS/featB LDS (conflict-free 16B/lane
// fragment reads), col-partitioned staging fused post-update (2 barriers/
// B-step), B's last iter pre-stages C, D reg-cached featB, F symmetric.

typedef __attribute__((ext_vector_type(8))) short short8;
typedef __attribute__((ext_vector_type(4))) float f32x4;

#define MFMA16(a, b, c) __builtin_amdgcn_mfma_f32_16x16x32_bf16(a, b, c, 0, 0, 0)

__device__ __forceinline__ float lrelu(float x) { return fmaxf(x, 0.01f * x); }

__device__ __forceinline__ ushort f2bf(float f) {
  unsigned u = __builtin_bit_cast(unsigned, f);
  u += 0x7fffu + ((u >> 16) & 1u);  // RNE
  return (ushort)(u >> 16);
}
__device__ __forceinline__ float bflo(unsigned u) {
  return __builtin_bit_cast(float, u << 16);
}
__device__ __forceinline__ unsigned pk2(float a, float b) {
  float2 t; t.x = a; t.y = b;
  __hip_bfloat162 h = __float22bfloat162_rn(t);
  unsigned u;
  __builtin_memcpy(&u, &h, 4);
  return u;
}

// d_ws layout (ushort): cfW1T@0 [4][64n][128k] | cfW2T@32768 [4][128n][64k]
// | f2fW1T@65536 | f2fW2T@81920 | f2iW1T@98304 | f2iW2T@114688
// | i2iW1T@131072 | i2iW2T@147456   ([128n][128k] each; 320KB total)

__global__ __launch_bounds__(256) void prep_weights(
    const float* __restrict__ cfW1, const float* __restrict__ cfW2,
    const float* __restrict__ f2fW1, const float* __restrict__ f2fW2,
    const float* __restrict__ f2iW1, const float* __restrict__ f2iW2,
    const float* __restrict__ i2iW1, const float* __restrict__ i2iW2,
    ushort* __restrict__ ws, float* __restrict__ out) {
  const int idx = (int)(blockIdx.x * 256 + threadIdx.x);
  if (idx == 0) out[2048] = 0.0f;  // com accumulator zero
  float v;
  if (idx < 32768) {          // cfW1 [f][k<128][n<64] -> [f][n][k]
    int f = idx >> 13, r = idx & 8191, n = r >> 7, k = r & 127;
    v = cfW1[f * 8192 + k * 64 + n];
  } else if (idx < 65536) {   // cfW2 [f][k<64][n<128] -> [f][n][k]
    int t = idx - 32768;
    int f = t >> 13, r = t & 8191, n = r >> 6, k = r & 63;
    v = cfW2[f * 8192 + k * 128 + n];
  } else {                    // 6 x [k<128][n<128] -> [n][k]
    int t = idx - 65536;
    int seg = t >> 14, r = t & 16383, n = r >> 7, k = r & 127;
    const float* W = (seg == 0) ? f2fW1 : (seg == 1) ? f2fW2 :
                     (seg == 2) ? f2iW1 : (seg == 3) ? f2iW2 :
                     (seg == 4) ? i2iW1 : i2iW2;
    v = W[k * 128 + n];
  }
  ws[idx] = f2bf(v);
}

__global__ __launch_bounds__(512, 2) void mfgn_kernel(
    const int* __restrict__ outfit_items,
    const float* __restrict__ items_feature,
    const int* __restrict__ items_neighbor,
    const float* __restrict__ cfb1, const float* __restrict__ cfb2,
    const float* __restrict__ f2fb1, const float* __restrict__ f2fb2,
    const float* __restrict__ f2ib1, const float* __restrict__ f2ib2,
    const float* __restrict__ i2ib1, const float* __restrict__ i2ib2,
    const float* __restrict__ o2sW, const float* __restrict__ o2sb,
    const ushort* __restrict__ wsW,
    float* __restrict__ out)
{
  __shared__ float facL[16 * 528];                                // 33792 B fp32 state
  __shared__ ushort prodS[8192] __attribute__((aligned(16)));     // 16 frags (mt,kt)
  __shared__ ushort hidS[8192] __attribute__((aligned(16)));      // 16 frags (mt,kt)
  __shared__ ushort featB[2048] __attribute__((aligned(16)));     // 4 frags (kt), 16 rows
  __shared__ float redE[8];
  __shared__ int oiL[16];
  __shared__ int clAll[256];
  __shared__ int ncAll[16];
  __shared__ int vslL[16];
  __shared__ int refcntL[16];
  __shared__ int nvsL;
  // frag unit (mt,kt,l): 8 ushorts at (kt*4+mt)*512 + l*8.
  // unit holds X[row = mt*16 + (l&15)][k = kt*32 + (l>>4)*8 .. +8].
  // fragment read = base + lane*16B -> contiguous, conflict-free.
  // featB: 16 rows only -> units (kt): kt*512 + l*8.
  // element (row,c) lives at (c>>5)*512 + (((c>>3)&3)*16 + row)*8 + (c&7).

  const int o = blockIdx.x;
  const int tid = (int)threadIdx.x;
  const int lane = tid & 63;
  const int wid = tid >> 6;        // wave owns output cols wid*16..+15
  const int n16 = lane & 15;
  const int q = lane >> 4;
  const int kb = q * 8;
  const int col = wid * 16 + n16;
  const int lx = lane * 8;         // fragment lane offset (ushorts)
  // col-partitioned staging: lane = prod row; wave owns k-cols [wid*16,+16)
  const int fS = lane & 3, ciS = lane >> 2;
  const int kc0 = wid * 16;
  const int q0 = (wid & 1) * 2;    // staged k-chunks are q-slots q0,q0+1 of kt=wid>>1
  const int sWA = ((wid >> 1) * 4 + (lane >> 4)) * 512 + (lane & 15) * 8;
  // hid write base for B/C (add mt*512) and D (mt=0)
  const int hwB = (wid >> 1) * 2048 + ((wid & 1) * 2 + (q >> 1)) * 128 + n16 * 8 + (q & 1) * 4;
  // featB element base for this lane's col (add item*8)
  const int fbCol = (col >> 5) * 512 + ((col >> 3) & 3) * 128 + (col & 7);

  // ---------------- load inputs ----------------
  if (tid < 16) oiL[tid] = outfit_items[o * 16 + tid];
  {
    const int n = tid >> 5, d0 = (tid & 31) * 4;
    float4 v = *(const float4*)(items_feature + o * 2048 + tid * 4);
    uint2 pk; pk.x = pk2(v.x, v.y); pk.y = pk2(v.z, v.w);
    *(uint2*)(featB + (d0 >> 5) * 512 + (((d0 >> 3) & 3) * 16 + n) * 8 + (d0 & 7)) = pk;
  }
  if (tid == 0) {
    int cnt = 0;
    for (int s = 0; s < 16; ++s) refcntL[s] = 0;
    for (int s = 0; s < 16; ++s) {
      int v = oiL[s];
      if (v != -1) { vslL[cnt++] = s; refcntL[v]++; }
    }
    nvsL = cnt;
  }
  for (int s = wid; s < 16; s += 8) {
    const int iv = outfit_items[o * 16 + s];
    if (iv == -1) { if (lane == 0) ncAll[s] = 0; continue; }
    int cand = -1;
    if (lane < 24) cand = (lane < 16) ? outfit_items[o * 16 + lane]
                                      : items_neighbor[o * 128 + iv * 8 + (lane - 16)];
    bool ok = (lane < 24) && (cand != -1) && (cand != iv);
    unsigned long long bm = __ballot(ok);
    if (ok) clAll[s * 16 + __popcll(bm & ((1ull << lane) - 1ull))] = cand;
    if (lane == 0) ncAll[s] = (int)__popcll(bm);
  }
  __syncthreads();
  const int nvs = nvsL;

  // ---------------- Phase A: creat_factors ----------------
  {
    const int f = wid & 3, half = wid >> 2;
    short8 wA[2][4];
#pragma unroll
    for (int etl = 0; etl < 2; ++etl)
#pragma unroll
      for (int kt = 0; kt < 4; ++kt)
        wA[etl][kt] = *(const short8*)(wsW + (f * 64 + (half * 2 + etl) * 16 + n16) * 128
                                       + kt * 32 + kb);
    f32x4 acc[2];
#pragma unroll
    for (int etl = 0; etl < 2; ++etl)
      acc[etl] = *(const f32x4*)(cfb1 + f * 64 + (half * 2 + etl) * 16 + q * 4);  // bias init
    __builtin_amdgcn_s_setprio(1);
    for (int kt = 0; kt < 4; ++kt) {
      short8 x = *(const short8*)(featB + kt * 512 + lx);
      acc[0] = MFMA16(wA[0][kt], x, acc[0]);
      acc[1] = MFMA16(wA[1][kt], x, acc[1]);
    }
    __builtin_amdgcn_s_setprio(0);
#pragma unroll
    for (int etl = 0; etl < 2; ++etl) {
      float h0 = lrelu(acc[etl][0]), h1 = lrelu(acc[etl][1]);
      float h2 = lrelu(acc[etl][2]), h3 = lrelu(acc[etl][3]);
      uint2 pk; pk.x = pk2(h0, h1); pk.y = pk2(h2, h3);
      // hid row f*16+n16, cols (half*2+etl)*16 + q*4 .. +3 (D2=64, kt_h=half)
      *(uint2*)(hidS + half * 2048 + f * 512 + (etl * 2 + (q >> 1)) * 128
                + n16 * 8 + (q & 1) * 4) = pk;
    }
    __syncthreads();
    short8 wB[4][2];
#pragma unroll
    for (int ctl = 0; ctl < 4; ++ctl)
#pragma unroll
      for (int kt = 0; kt < 2; ++kt)
        wB[ctl][kt] = *(const short8*)(wsW + 32768 + (f * 128 + half * 64 + ctl * 16 + n16) * 64
                                       + kt * 32 + kb);
    f32x4 acc2[4];
#pragma unroll
    for (int ctl = 0; ctl < 4; ++ctl) {
      float b2 = cfb2[f * 128 + half * 64 + ctl * 16 + n16];
      acc2[ctl] = (f32x4){b2, b2, b2, b2};  // bias init
    }
    __builtin_amdgcn_s_setprio(1);
    for (int kt = 0; kt < 2; ++kt) {
      short8 h = *(const short8*)(hidS + (kt * 4 + f) * 512 + lx);
#pragma unroll
      for (int ctl = 0; ctl < 4; ++ctl) acc2[ctl] = MFMA16(h, wB[ctl][kt], acc2[ctl]);
    }
    __builtin_amdgcn_s_setprio(0);
#pragma unroll
    for (int ctl = 0; ctl < 4; ++ctl) {
      int c = half * 64 + ctl * 16 + n16;
#pragma unroll
      for (int r = 0; r < 4; ++r)
        facL[(q * 4 + r) * 528 + f * 132 + c] = lrelu(acc2[ctl][r]);
    }
    __syncthreads();
  }

  // ---------------- Phase B: inter_factors (2 barriers/step) ----------------
  {
    short8 w1f[4], w2f[4];
#pragma unroll
    for (int kt = 0; kt < 4; ++kt) {
      w1f[kt] = *(const short8*)(wsW + 65536 + col * 128 + kt * 32 + kb);
      w2f[kt] = *(const short8*)(wsW + 81920 + col * 128 + kt * 32 + kb);
    }
    const f32x4 b1q = *(const f32x4*)(f2fb1 + wid * 16 + q * 4);
    const float b2v = f2fb2[col];

    // stage prod rows for slot s into frag layout (this wave's k-cols only)
    auto stageB = [&](int s, int iv_, int nc_) {
      if (ciS < nc_) {
        const int cit = clAll[s * 16 + ciS];
        const float* tp = facL + iv_ * 528 + fS * 132 + kc0;
        const float* cp = facL + cit * 528 + fS * 132 + kc0;
#pragma unroll
        for (int g = 0; g < 2; ++g) {
          float4 a0 = *(const float4*)(tp + g * 8), a1 = *(const float4*)(tp + g * 8 + 4);
          float4 c0 = *(const float4*)(cp + g * 8), c1 = *(const float4*)(cp + g * 8 + 4);
          uint4 u4;
          u4.x = pk2(a0.x * c0.x, a0.y * c0.y); u4.y = pk2(a0.z * c0.z, a0.w * c0.w);
          u4.z = pk2(a1.x * c1.x, a1.y * c1.y); u4.w = pk2(a1.z * c1.z, a1.w * c1.w);
          *(uint4*)(prodS + sWA + (q0 + g) * 128) = u4;
        }
      }
      // rows >= 4*nc stale: finite bf16, epilogue-masked (MLP row-separable)
    };
    // stage Phase C's input: bf16(fac[item=ciS][fS][k]) in frag layout
    auto stageC = [&]() {
      const float* sp = facL + ciS * 528 + fS * 132 + kc0;
#pragma unroll
      for (int g = 0; g < 2; ++g) {
        float4 a0 = *(const float4*)(sp + g * 8), a1 = *(const float4*)(sp + g * 8 + 4);
        uint4 u4;
        u4.x = pk2(a0.x, a0.y); u4.y = pk2(a0.z, a0.w);
        u4.z = pk2(a1.x, a1.y); u4.w = pk2(a1.z, a1.w);
        *(uint4*)(prodS + sWA + (q0 + g) * 128) = u4;
      }
    };

    if (nvs > 0) { const int s0 = vslL[0]; stageB(s0, oiL[s0], ncAll[s0]); }
    __syncthreads();  // [b1] products for step 0 ready

    for (int u = 0; u < nvs; ++u) {
      const int s = vslL[u];
      const int iv = oiL[s];
      const int nc = ncAll[s];
      // L1 swapped: unrolled 4 tiles, bias-initialized acc
      f32x4 acc[4];
#pragma unroll
      for (int mt = 0; mt < 4; ++mt) acc[mt] = b1q;
      __builtin_amdgcn_s_setprio(1);
      for (int kt = 0; kt < 4; ++kt)
#pragma unroll
        for (int mt = 0; mt < 4; ++mt) {
          short8 x = *(const short8*)(prodS + (kt * 4 + mt) * 512 + lx);
          acc[mt] = MFMA16(w1f[kt], x, acc[mt]);
        }
      __builtin_amdgcn_s_setprio(0);
#pragma unroll
      for (int mt = 0; mt < 4; ++mt) {
        float h0 = lrelu(acc[mt][0]), h1 = lrelu(acc[mt][1]);
        float h2 = lrelu(acc[mt][2]), h3 = lrelu(acc[mt][3]);
        uint2 pk; pk.x = pk2(h0, h1); pk.y = pk2(h2, h3);
        *(uint2*)(hidS + hwB + mt * 512) = pk;
      }
      __syncthreads();  // [b2] hid ready
      // L2 normal: unrolled 4 tiles, bias-initialized acc
      f32x4 acc2[4];
#pragma unroll
      for (int mt = 0; mt < 4; ++mt) acc2[mt] = (f32x4){b2v, b2v, b2v, b2v};
      __builtin_amdgcn_s_setprio(1);
      for (int kt = 0; kt < 4; ++kt)
#pragma unroll
        for (int mt = 0; mt < 4; ++mt) {
          short8 h = *(const short8*)(hidS + (kt * 4 + mt) * 512 + lx);
          acc2[mt] = MFMA16(h, w2f[kt], acc2[mt]);
        }
      __builtin_amdgcn_s_setprio(0);
      // epilogue: rows ci*4+f (f=reg); mask ci=mt*4+q<nc; sum over ci
      float part[4] = {0.f, 0.f, 0.f, 0.f};
#pragma unroll
      for (int mt = 0; mt < 4; ++mt) {
        bool act = (mt * 4 + q) < nc;
        if (act) {
#pragma unroll
          for (int r = 0; r < 4; ++r) part[r] += lrelu(acc2[mt][r]);
        }
      }
#pragma unroll
      for (int r = 0; r < 4; ++r) {
        float v = part[r];
        v += __shfl_xor(v, 16);
        v += __shfl_xor(v, 32);
        part[r] = v;
      }
      if (q == 0) {  // wave owns cols exclusively -> plain fp32 +=
#pragma unroll
        for (int r = 0; r < 4; ++r)
          facL[iv * 528 + r * 132 + col] += part[r];
      }
      // fused next-stage: update touched only this wave's cols; staging
      // reads only this wave's cols -> same-wave DS order, NO barrier.
      if (u + 1 < nvs) {
        const int s2 = vslL[u + 1];
        stageB(s2, oiL[s2], ncAll[s2]);
      } else {
        stageC();
      }
      __syncthreads();  // [b1] next products (or Phase C input) ready
    }
    if (nvs == 0) { stageC(); __syncthreads(); }  // robustness (unused outputs)
  }

  // ---------------- Phase C: infer_items (input pre-staged by B) ----------------
  {
    short8 w1f[4], w2f[4];
#pragma unroll
    for (int kt = 0; kt < 4; ++kt) {
      w1f[kt] = *(const short8*)(wsW + 98304 + col * 128 + kt * 32 + kb);
      w2f[kt] = *(const short8*)(wsW + 114688 + col * 128 + kt * 32 + kb);
    }
    const f32x4 b1q = *(const f32x4*)(f2ib1 + wid * 16 + q * 4);
    const float b2v = f2ib2[col];
    f32x4 acc[4];
#pragma unroll
    for (int mt = 0; mt < 4; ++mt) acc[mt] = b1q;
    __builtin_amdgcn_s_setprio(1);
    for (int kt = 0; kt < 4; ++kt)
#pragma unroll
      for (int mt = 0; mt < 4; ++mt) {
        short8 x = *(const short8*)(prodS + (kt * 4 + mt) * 512 + lx);
        acc[mt] = MFMA16(w1f[kt], x, acc[mt]);
      }
    __builtin_amdgcn_s_setprio(0);
#pragma unroll
    for (int mt = 0; mt < 4; ++mt) {
      float h0 = lrelu(acc[mt][0]), h1 = lrelu(acc[mt][1]);
      float h2 = lrelu(acc[mt][2]), h3 = lrelu(acc[mt][3]);
      uint2 pk; pk.x = pk2(h0, h1); pk.y = pk2(h2, h3);
      *(uint2*)(hidS + hwB + mt * 512) = pk;
    }
    __syncthreads();
    f32x4 acc2[4];
#pragma unroll
    for (int mt = 0; mt < 4; ++mt) acc2[mt] = (f32x4){b2v, b2v, b2v, b2v};
    __builtin_amdgcn_s_setprio(1);
    for (int kt = 0; kt < 4; ++kt)
#pragma unroll
      for (int mt = 0; mt < 4; ++mt) {
        short8 h = *(const short8*)(hidS + (kt * 4 + mt) * 512 + lx);
        acc2[mt] = MFMA16(h, w2f[kt], acc2[mt]);
      }
    __builtin_amdgcn_s_setprio(0);
#pragma unroll
    for (int mt = 0; mt < 4; ++mt) {
      int item = mt * 4 + q;  // rows = item*4+f, f=reg
      float g = 0.f;
#pragma unroll
      for (int r = 0; r < 4; ++r) g += lrelu(acc2[mt][r]);
      int a = fbCol + item * 8;  // unique (item,col) per lane
      featB[a] = f2bf(bflo((unsigned)featB[a]) + (float)refcntL[item] * g);
    }
    __syncthreads();
  }

  // ---------------- Phase D: inter_items (featB A-fragments reg-cached) ----------------
  {
    short8 w1f[4], w2f[4];
#pragma unroll
    for (int kt = 0; kt < 4; ++kt) {
      w1f[kt] = *(const short8*)(wsW + 131072 + col * 128 + kt * 32 + kb);
      w2f[kt] = *(const short8*)(wsW + 147456 + col * 128 + kt * 32 + kb);
    }
    const f32x4 b1q = *(const f32x4*)(i2ib1 + wid * 16 + q * 4);
    const float b2v = i2ib2[col];
    short8 xc[4];
#pragma unroll
    for (int kt = 0; kt < 4; ++kt)
      xc[kt] = *(const short8*)(featB + kt * 512 + lx);

    for (int u = 0; u < nvs; ++u) {
      const int iv = oiL[vslL[u]];
      f32x4 acc = b1q;
      __builtin_amdgcn_s_setprio(1);
      for (int kt = 0; kt < 4; ++kt) acc = MFMA16(w1f[kt], xc[kt], acc);
      __builtin_amdgcn_s_setprio(0);
      {
        float h0 = lrelu(acc[0]), h1 = lrelu(acc[1]);
        float h2 = lrelu(acc[2]), h3 = lrelu(acc[3]);
        uint2 pk; pk.x = pk2(h0, h1); pk.y = pk2(h2, h3);
        *(uint2*)(hidS + hwB) = pk;   // rows n16 -> mt=0 frags
      }
      __syncthreads();
      f32x4 acc2 = (f32x4){b2v, b2v, b2v, b2v};
      __builtin_amdgcn_s_setprio(1);
      for (int kt = 0; kt < 4; ++kt) {
        short8 h = *(const short8*)(hidS + kt * 2048 + lx);
        acc2 = MFMA16(h, w2f[kt], acc2);
      }
      __builtin_amdgcn_s_setprio(0);
      // msgs summed per item with weight = (item==iv) ? 0 : refcnt[item]
      float part = 0.f;
#pragma unroll
      for (int r = 0; r < 4; ++r) {
        int item = q * 4 + r;
        float w = (item == iv) ? 0.0f : (float)refcntL[item];
        part += w * lrelu(acc2[r]);
      }
      part += __shfl_xor(part, 16);
      part += __shfl_xor(part, 32);
      if (q == 0) {
        int a = fbCol + iv * 8;
        featB[a] = f2bf(bflo((unsigned)featB[a]) + part);
      }
      __syncthreads();
      // refresh cached featB row iv (only lanes whose fragment row changed);
      // next update happens only after the next barrier -> no race
      if (n16 == iv) {
#pragma unroll
        for (int kt = 0; kt < 4; ++kt)
          xc[kt] = *(const short8*)(featB + kt * 512 + lx);
      }
    }
  }

  // ---------------- Phase E: infer_outfit + score ----------------
  if (tid < 128) {
    const int eb = (tid >> 5) * 512 + ((tid >> 3) & 3) * 128 + (tid & 7);
    float sum = 0.0f;
    for (int u = 0; u < nvs; ++u) {
      int it = oiL[vslL[u]];
      sum += bflo((unsigned)featB[eb + it * 8]);
    }
    float v = sum * o2sW[tid];
#pragma unroll
    for (int off = 1; off < 64; off <<= 1) v += __shfl_xor(v, off);
    if (lane == 0) redE[wid] = v;
  }
  __syncthreads();
  if (tid == 0) {
    float t = redE[0] + redE[1] + o2sb[0];
    out[o] = 1.0f / (1.0f + expf(-t));
  }

  // ---------------- Phase F: com_loss (symmetric: f<=g only, x2 off-diag) ----------------
  {
    const int n = tid >> 5, f = (tid >> 3) & 3, g = (tid >> 1) & 3, h = tid & 1;
    float dot = 0.0f;
    if (f <= g) {
      const float* pa = facL + n * 528 + f * 132 + h * 64;
      const float* pb = facL + n * 528 + g * 132 + h * 64;
      for (int i = 0; i < 16; ++i) {
        float4 a = *(const float4*)(pa + i * 4);
        float4 b = *(const float4*)(pb + i * 4);
        dot += a.x * b.x + a.y * b.y + a.z * b.z + a.w * b.w;
      }
    }
    dot += __shfl_xor(dot, 1);  // combine k-halves
    float v = dot - ((f == g) ? 1.0f : 0.0f);
    float wgt = (f == g) ? 1.0f : 2.0f;
    float sq = (h == 0 && f <= g && oiL[n] != -1) ? wgt * v * v : 0.0f;
#pragma unroll
    for (int off = 1; off < 64; off <<= 1) sq += __shfl_xor(sq, off);
    __syncthreads();  // E's redE read complete before overwrite
    if (lane == 0) redE[wid] = sq;
    __syncthreads();
    if (tid == 0) {
      float tot = 0.f;
#pragma unroll
      for (int w = 0; w < 8; ++w) tot += redE[w];
      atomicAdd(out + 2048, tot * (1.0f / 2048.0f));
    }
  }
}

extern "C" void kernel_launch(void* const* d_in, const int* in_sizes, int n_in,
                              void* d_out, int out_size, void* d_ws, size_t ws_size,
                              hipStream_t stream) {
  float* out = (float*)d_out;
  ushort* ws = (ushort*)d_ws;  // needs 320KB
  hipLaunchKernelGGL(prep_weights, dim3(640), dim3(256), 0, stream,
                     (const float*)d_in[4], (const float*)d_in[6],
                     (const float*)d_in[8], (const float*)d_in[10],
                     (const float*)d_in[12], (const float*)d_in[14],
                     (const float*)d_in[16], (const float*)d_in[18],
                     ws, out);
  hipLaunchKernelGGL(mfgn_kernel, dim3(2048), dim3(512), 0, stream,
                     (const int*)d_in[0],
                     (const float*)d_in[1],
                     (const int*)d_in[2],
                     // d_in[3] items_factors unused; weights via ws
                     (const float*)d_in[5], (const float*)d_in[7],
                     (const float*)d_in[9], (const float*)d_in[11],
                     (const float*)d_in[13], (const float*)d_in[15],
                     (const float*)d_in[17], (const float*)d_in[19],
                     (const float*)d_in[20], (const float*)d_in[21],
                     (const ushort*)ws,
                     out);
}